// Round 9
// baseline (326.370 us; speedup 1.0000x reference)
//
#include <hip/hip_runtime.h>

// Fused GQA attention block: QKV proj(+RoPE, +V-transpose) -> flash attn -> out proj.
// B=2 S=2048 D=2048 H=16 KV=4 HD=128. All MFMA compute in bf16 (tol = 2% of max).

#define B_  2
#define S_  2048
#define D_  2048
#define H_  16
#define KV_ 4
#define HD_ 128
#define NQK 2560    // QK buffer row stride: 2048 (Q) + 512 (K); V goes to Vt directly

typedef unsigned short ushort_t;
typedef __attribute__((ext_vector_type(8))) __bf16 bf16x8;
typedef __attribute__((ext_vector_type(4))) float  f32x4;

__device__ __forceinline__ ushort_t f2bf(float f) {
    unsigned u = __float_as_uint(f);
    u += 0x7FFFu + ((u >> 16) & 1u);          // round-to-nearest-even
    return (ushort_t)(u >> 16);
}
__device__ __forceinline__ float bf2f(ushort_t h) {
    return __uint_as_float(((unsigned)h) << 16);
}

// async global->LDS, 16B per lane; LDS dest = wave-uniform base + lane*16
__device__ __forceinline__ void g2l16(const void* g, void* l) {
    __builtin_amdgcn_global_load_lds(
        (const __attribute__((address_space(1))) unsigned int*)g,
        (__attribute__((address_space(3))) unsigned int*)l, 16, 0, 0);
}

// ---------------- fused prep: x->bf16, 4 weight transposes, bias pack -------

__global__ __launch_bounds__(256) void k_prep(
    const float* __restrict__ x,  ushort_t* __restrict__ xb,
    const float* __restrict__ Wq, const float* __restrict__ Wk,
    const float* __restrict__ Wv, const float* __restrict__ Wo,
    ushort_t* __restrict__ Wt, ushort_t* __restrict__ Wot,
    const float* __restrict__ bq, const float* __restrict__ bk,
    const float* __restrict__ bv, float* __restrict__ bb) {
    __shared__ float tile[32][33];
    int id = blockIdx.x, t = threadIdx.x;
    if (id < 8192) {                                   // x fp32 -> bf16
        int i = id * 256 + t;
        float4 v = ((const float4*)x)[i];
        ushort4 o;
        o.x = f2bf(v.x); o.y = f2bf(v.y); o.z = f2bf(v.z); o.w = f2bf(v.w);
        ((ushort4*)xb)[i] = o;
        return;
    }
    const float* src; ushort_t* dst; int C, bid;
    if (id < 12288)      { src = Wq; dst = Wt;                       C = 2048; bid = id - 8192;  }
    else if (id < 13312) { src = Wk; dst = Wt + (size_t)2048 * 2048; C = 512;  bid = id - 12288; }
    else if (id < 14336) { src = Wv; dst = Wt + (size_t)2560 * 2048; C = 512;  bid = id - 13312; }
    else if (id < 18432) { src = Wo; dst = Wot;                      C = 2048; bid = id - 14336; }
    else {                                             // bias pack
        int i = (id - 18432) * 256 + t;
        if (i < 3072)
            bb[i] = (i < 2048) ? bq[i] : (i < 2560) ? bk[i - 2048] : bv[i - 2560];
        return;
    }
    const int R = 2048;
    int nbc = C >> 5;
    int c0 = (bid % nbc) * 32, r0 = (bid / nbc) * 32;
    int tx = t & 31, ty = t >> 5;
    for (int i = ty; i < 32; i += 8)
        tile[i][tx] = src[(size_t)(r0 + i) * C + c0 + tx];
    __syncthreads();
    for (int i = ty; i < 32; i += 8)
        dst[(size_t)(c0 + i) * R + r0 + tx] = f2bf(tile[tx][i]);
}

// ------ GEMM, producer-consumer waves: C[M,N] = A[M,K]*Bt[N,K]^T (+extras) ----
// r9 structure: 512 threads = 4 CONSUMER waves (MFMA only; no outstanding
// vmcnt -> their s_barrier is cheap) + 4 PRODUCER waves (g2l16 only; their
// per-wave vmcnt(0) drain before the barrier overlaps consumer MFMA on the
// same SIMDs — m114 co-scheduling). Double-buffered BK=64 LDS (64 KB ->
// 2 blocks/CU, 16 waves, 128-VGPR cap; consumer set ~112 regs fits).
// Tile 128x128; consumer wave w<4 computes 64x64 quadrant (4x4 c-tiles).
// LDS layout identical to r7 (conflict-free): 128B rows, slot granule g holds
// global granule g ^ (row&7); read swizzle rsw=l16&7. XCD m-stripe swizzle (r6).
// gemm1 extras: RoPE on cols<2560 (pre-rounding), V cols -> transposed Vt.

__global__ __launch_bounds__(512, 4) void k_gemm(const ushort_t* __restrict__ A,
                                                 const ushort_t* __restrict__ Bt,
                                                 void* __restrict__ Cp,
                                                 const float* __restrict__ bias,
                                                 const float* __restrict__ fc,
                                                 const float* __restrict__ fs,
                                                 ushort_t* __restrict__ Vt,
                                                 int M, int N, int K, int out_bf16) {
    __shared__ __align__(16) ushort_t As[2 * 128 * 64];
    __shared__ __align__(16) ushort_t Bs[2 * 128 * 64];
    int t = threadIdx.x;
    int w = t >> 6, lane = t & 63, quad = lane >> 4, l16 = lane & 15;
    int L = blockIdx.x;
    int mper = (M >> 7) >> 3;                 // m-tiles per XCD
    int xcd = L & 7, j = L >> 3;
    int m0 = (xcd * mper + (j % mper)) * 128;
    int n0 = (j / mper) * 128;
    bool producer = (w >= 4);
    int wq = w & 3;
    int wm = (wq >> 1) * 64, wn = (wq & 1) * 64;   // consumer quadrant
    int rsw = l16 & 7;                             // read-side swizzle
    f32x4 acc[4][4] = {};

    int rlo = lane >> 3;                      // producer: row within 8-row round
    int gsl = lane & 7;                       // producer: slot granule
    const ushort_t* Ag = A  + (size_t)(m0 + wq * 32) * K;
    const ushort_t* Bg = Bt + (size_t)(n0 + wq * 32) * K;

#define STAGE(K0, BUF)                                                           \
    do {                                                                         \
        _Pragma("unroll")                                                        \
        for (int p = 0; p < 4; p++) {                                            \
            int row = p * 8 + rlo;                                               \
            int gs = gsl ^ (row & 7);                                            \
            g2l16(Ag + (size_t)row * K + (K0) + gs * 8,                          \
                  (char*)As + (BUF) * 16384 + (wq * 32 + p * 8) * 128);          \
            g2l16(Bg + (size_t)row * K + (K0) + gs * 8,                          \
                  (char*)Bs + (BUF) * 16384 + (wq * 32 + p * 8) * 128);          \
        }                                                                        \
    } while (0)

    if (producer) STAGE(0, 0);
    __syncthreads();

    for (int k0 = 0; k0 < K; k0 += 64) {
        int cur = (k0 >> 6) & 1;
        if (producer) {
            if (k0 + 64 < K) STAGE(k0 + 64, cur ^ 1);   // prefetch next K-chunk
        } else {
            const ushort_t* Asc = As + cur * 8192;
            const ushort_t* Bsc = Bs + cur * 8192;
#pragma unroll
            for (int kc = 0; kc < 2; kc++) {
                int gg = quad + kc * 4;
                bf16x8 af[4], bfr[4];
#pragma unroll
                for (int i = 0; i < 4; i++)
                    af[i] = *(const bf16x8*)(Asc + (wm + i * 16 + l16) * 64 + ((gg ^ rsw) * 8));
#pragma unroll
                for (int j2 = 0; j2 < 4; j2++)
                    bfr[j2] = *(const bf16x8*)(Bsc + (wn + j2 * 16 + l16) * 64 + ((gg ^ rsw) * 8));
#pragma unroll
                for (int i = 0; i < 4; i++)
#pragma unroll
                    for (int j2 = 0; j2 < 4; j2++)
                        acc[i][j2] = __builtin_amdgcn_mfma_f32_16x16x32_bf16(af[i], bfr[j2], acc[i][j2], 0, 0, 0);
            }
        }
        __syncthreads();   // consumers done reading buf cur; producers done staging cur^1
    }
#undef STAGE

    if (producer) return;
    // epilogue (consumers only): C/D layout col=lane&15, row=quad*4+reg
    int ostride = fc ? NQK : N;               // gemm1 writes QK buffer (stride 2560)
#pragma unroll
    for (int i = 0; i < 4; i++) {
        int r = m0 + wm + i * 16 + quad * 4;
#pragma unroll
        for (int j2 = 0; j2 < 4; j2++) {
            int c = n0 + wn + j2 * 16 + l16;
            float bv_ = bias ? bias[c] : 0.f;
            if (fc && c >= 2560) {                    // V cols -> transposed to Vt
                ushort4 pack;
                pack.x = f2bf(acc[i][j2][0] + bv_);
                pack.y = f2bf(acc[i][j2][1] + bv_);
                pack.z = f2bf(acc[i][j2][2] + bv_);
                pack.w = f2bf(acc[i][j2][3] + bv_);
                int kv = (c - 2560) >> 7, d = (c - 2560) & 127;
                int b = r >> 11, s0 = r & (S_ - 1);
                *(ushort4*)&Vt[(((size_t)b * KV_ + kv) * HD_ + d) * S_ + s0] = pack;
                continue;
            }
#pragma unroll
            for (int jr = 0; jr < 4; jr++) {
                float v = acc[i][j2][jr] + bv_;
                if (fc) {                             // fused RoPE on Q,K cols
                    int s  = (r + jr) & (S_ - 1);
                    int dp = (c & 127) >> 1;
                    float cs = fc[s * 64 + dp], sn = fs[s * 64 + dp];
                    float p = __shfl_xor(v, 1);       // pair element (c^1)
                    v = (c & 1) ? (v * cs + p * sn) : (v * cs - p * sn);
                }
                if (out_bf16) ((ushort_t*)Cp)[(size_t)(r + jr) * ostride + c] = f2bf(v);
                else          ((float*)Cp)[(size_t)(r + jr) * ostride + c] = v;
            }
        }
    }
}

// ---------------- Flash attention v5: double-buffered staging ----------------
// grid (S/128, H, B); block 512 = 8 waves; wave w owns q rows qt*128+w*16..+15.
// Waves 0-3 stage K, waves 4-7 stage V; tile kt+1 prefetched into the other
// LDS buffer before computing kt. LDS 80 KB -> 2 blocks/CU. XOR bank swizzle
// on K/V granules. Max-free softmax; l via MFMA with ones-B.
// launch_bounds(512,4): 128-VGPR cap ((512,6) spilled — round 2).

__global__ __launch_bounds__(512, 4) void k_flash(const ushort_t* __restrict__ QK,
                                                  const ushort_t* __restrict__ Vt,
                                                  ushort_t* __restrict__ AO) {
    __shared__ __align__(16) ushort_t Ks[2 * 8192];
    __shared__ __align__(16) ushort_t Vs[2 * 8192];
    __shared__ __align__(16) ushort_t Ps[8 * 16 * 64];
    int h = blockIdx.y, b = blockIdx.z;
    int qt = b ? ((int)gridDim.x - 1 - (int)blockIdx.x) : (int)blockIdx.x;
    int kvh = h >> 2;
    int t = threadIdx.x, w = t >> 6, lane = t & 63, quad = lane >> 4, l16 = lane & 15;
    int qrow0 = qt * 128 + w * 16;
    const float SOFT = 0.08838834764831845f * 1.4426950408889634f; // 1/sqrt(128)*log2(e)

    bf16x8 aq[4];
    {
        const ushort_t* qb = QK + (size_t)(b * S_ + qrow0 + l16) * NQK + h * HD_ + quad * 8;
#pragma unroll
        for (int kc = 0; kc < 4; kc++) aq[kc] = *(const bf16x8*)(qb + kc * 32);
    }
    bf16x8 vone;
#pragma unroll
    for (int i = 0; i < 8; i++) vone[i] = (__bf16)1.0f;

    f32x4 o[8] = {};
    f32x4 ol = {};                 // row-sum accumulator (softmax denominator)
    ushort_t* Psw = Ps + w * 16 * 64;
    int gsw = (l16 >> 1) & 3;      // read-side swizzle bits

    const ushort_t* kgb = QK + (size_t)(b * S_) * NQK + 2048 + kvh * HD_;
    const ushort_t* vgb = Vt + ((size_t)(b * KV_ + kvh) * HD_) * S_;

    int sr, sgs; char *sK0, *sV0;
    if (t < 256) {
        sr = t >> 2; sgs = (t & 3) ^ ((sr >> 1) & 3);
        sK0 = (char*)Ks + (t >> 6) * 1024;
        sV0 = nullptr;
    } else {
        int u = t - 256;
        sr = u >> 2; sgs = (u & 3) ^ ((sr >> 1) & 3);
        sV0 = (char*)Vs + ((t - 256) >> 6) * 1024;
        sK0 = nullptr;
    }

#define STAGE(KT, BUF)                                                          \
    do {                                                                        \
        if (t < 256) {                                                          \
            const ushort_t* kg = kgb + (size_t)((KT) * 64 + sr) * NQK + sgs * 8; \
            char* KsW = sK0 + (BUF) * 16384;                                    \
            _Pragma("unroll")                                                   \
            for (int p = 0; p < 4; p++) g2l16(kg + p * 32, KsW + p * 4096);     \
        } else {                                                                \
            const ushort_t* vg = vgb + (KT) * 64 + sgs * 8 + (size_t)sr * S_;   \
            char* VsW = sV0 + (BUF) * 16384;                                    \
            _Pragma("unroll")                                                   \
            for (int p = 0; p < 4; p++)                                         \
                g2l16(vg + (size_t)((p & 1) * 64) * S_ + (p >> 1) * 32, VsW + p * 4096); \
        }                                                                       \
    } while (0)

    int ktmax = 2 * qt + 1;
    STAGE(0, 0);
    __syncthreads();

    for (int kt = 0; kt <= ktmax; kt++) {
        int cur = kt & 1;
        if (kt < ktmax) STAGE(kt + 1, cur ^ 1);   // prefetch next tile

        if (kt * 64 <= qrow0 + 15) {              // else fully-masked for this wave
            const ushort_t* Kc = Ks + cur * 8192;
            const ushort_t* Vc = Vs + cur * 8192;
            f32x4 sacc[4] = {};
#pragma unroll
            for (int kc = 0; kc < 4; kc++)
#pragma unroll
                for (int nb = 0; nb < 4; nb++) {
                    bf16x8 bk = *(const bf16x8*)(Kc + kc * 2048 + (nb * 16 + l16) * 32 + ((quad ^ gsw) * 8));
                    sacc[nb] = __builtin_amdgcn_mfma_f32_16x16x32_bf16(aq[kc], bk, sacc[nb], 0, 0, 0);
                }
            if (kt * 64 + 63 > qrow0) {           // diagonal tile: causal mask
#pragma unroll
                for (int nb = 0; nb < 4; nb++)
#pragma unroll
                    for (int jr = 0; jr < 4; jr++) {
                        int kcol = kt * 64 + nb * 16 + l16;
                        int qr = qrow0 + quad * 4 + jr;
                        if (kcol > qr) sacc[nb][jr] = -1e30f;
                    }
            }
#pragma unroll
            for (int nb = 0; nb < 4; nb++)
#pragma unroll
                for (int jr = 0; jr < 4; jr++)
                    Psw[(quad * 4 + jr) * 64 + nb * 16 + l16] = f2bf(exp2f(sacc[nb][jr] * SOFT));

            asm volatile("s_waitcnt lgkmcnt(0)" ::: "memory");  // P writes -> A-frag reads

#pragma unroll
            for (int kc2 = 0; kc2 < 2; kc2++) {
                bf16x8 ap = *(const bf16x8*)(Psw + l16 * 64 + kc2 * 32 + quad * 8);
                ol = __builtin_amdgcn_mfma_f32_16x16x32_bf16(ap, vone, ol, 0, 0, 0);
#pragma unroll
                for (int db = 0; db < 8; db++) {
                    bf16x8 bv = *(const bf16x8*)(Vc + kc2 * 4096 + (db * 16 + l16) * 32 + ((quad ^ gsw) * 8));
                    o[db] = __builtin_amdgcn_mfma_f32_16x16x32_bf16(ap, bv, o[db], 0, 0, 0);
                }
            }
        }
        __syncthreads();   // next tile staged + this tile's LDS reads done
    }
#undef STAGE

    // epilogue: divide by l, write bf16
#pragma unroll
    for (int jr = 0; jr < 4; jr++) {
        float inv = 1.0f / ol[jr];
        size_t rbase = (size_t)(b * S_ + qrow0 + quad * 4 + jr) * D_ + h * HD_;
#pragma unroll
        for (int db = 0; db < 8; db++)
            AO[rbase + db * 16 + l16] = f2bf(o[db][jr] * inv);
    }
}

// ---------------- launch ----------------

extern "C" void kernel_launch(void* const* d_in, const int* in_sizes, int n_in,
                              void* d_out, int out_size, void* d_ws, size_t ws_size,
                              hipStream_t stream) {
    const float* x  = (const float*)d_in[0];
    // d_in[1] = mask (all zeros; reference ignores it — causal built in-kernel)
    const float* fc = (const float*)d_in[2];
    const float* fs = (const float*)d_in[3];
    const float* Wq = (const float*)d_in[4];
    const float* bq = (const float*)d_in[5];
    const float* Wk = (const float*)d_in[6];
    const float* bk = (const float*)d_in[7];
    const float* Wv = (const float*)d_in[8];
    const float* bv = (const float*)d_in[9];
    const float* Wo = (const float*)d_in[10];

    char* ws = (char*)d_ws;
    // layout (bytes); AO aliases xb (xb dead after gemm1). Vt is its own 4 MB
    // (must NOT alias Wt: gemm1 reads Wt while writing Vt). QK stride 2560.
    ushort_t* xb  = (ushort_t*)(ws);                 // 16 MB  (4096x2048 bf16)
    ushort_t* Wt  = (ushort_t*)(ws + 16777216);      // 12 MB  (3072x2048 bf16)
    ushort_t* Wot = (ushort_t*)(ws + 29360128);      //  8 MB  (2048x2048 bf16)
    float*    bb  = (float*)   (ws + 37748736);      // 12 KB
    ushort_t* QK  = (ushort_t*)(ws + 37761024);      // 20 MB  (4096x2560 bf16)
    ushort_t* Vt  = (ushort_t*)(ws + 58732544);      //  4 MB  (2*4*128*2048 bf16)
    ushort_t* AO  = xb;                              // 16 MB  (4096x2048 bf16)
    float* out = (float*)d_out;

    k_prep<<<18444, 256, 0, stream>>>(x, xb, Wq, Wk, Wv, Wo, Wt, Wot, bq, bk, bv, bb);
    k_gemm<<<768, 512, 0, stream>>>(xb, Wt, QK, bb, fc, fs, Vt, 4096, 3072, 2048, 1);
    k_flash<<<dim3(16, 16, 2), 512, 0, stream>>>(QK, Vt, AO);
    k_gemm<<<512, 512, 0, stream>>>(AO, Wot, out, nullptr, nullptr, nullptr, nullptr,
                                    4096, 2048, 2048, 0);
}